// Round 4
// baseline (321.646 us; speedup 1.0000x reference)
//
#include <hip/hip_runtime.h>
#include <hip/hip_bf16.h>
#include <math.h>

typedef __hip_bfloat16 bf16;
typedef __attribute__((ext_vector_type(8))) short short8;
typedef __attribute__((ext_vector_type(4))) float floatx4;

#define D_MODEL 1024
#define NUM_HEADS 16
#define DK 64
#define SEQ 2048
#define BATCH 2
#define MROWS (BATCH * SEQ)          // 4096
#define KDIM 1024
#define SEG_X ((size_t)MROWS * D_MODEL)      // 4194304
#define SEG_W ((size_t)D_MODEL * D_MODEL)    // 1048576
#define QKSTRIDE 2048                         // fused Q|K row stride
#define ROPE_C (-9.2103403719761836f / 64.f)  // -ln(10000)/dk
// Q prescale: dk^-0.5 * log2(e)  -> scores arrive in log2 domain, P = exp2(S)
#define QSCALE (0.125f * 1.4426950408889634f)

__device__ inline void gload16(const void* g, void* l) {
    __builtin_amdgcn_global_load_lds(
        (const __attribute__((address_space(1))) void*)g,
        (__attribute__((address_space(3))) void*)l, 16, 0, 0);
}

// ---------------------------------------------------------------------------
// Cast fp32 inputs to bf16 workspace buffers.
// ---------------------------------------------------------------------------
__global__ __launch_bounds__(256) void cast_kernel(
    const float* __restrict__ x,  const float* __restrict__ Wq,
    const float* __restrict__ Wk, const float* __restrict__ Wv,
    const float* __restrict__ Wo,
    bf16* __restrict__ xb, bf16* __restrict__ w_all, bf16* __restrict__ wob)
{
    const size_t i = ((size_t)blockIdx.x * 256 + threadIdx.x) * 4;
    const float* src; bf16* dst;
    if (i < SEG_X)                    { src = x  + i;                       dst = xb + i; }
    else if (i < SEG_X + SEG_W)       { src = Wq + (i - SEG_X);             dst = w_all + (i - SEG_X); }
    else if (i < SEG_X + 2 * SEG_W)   { src = Wk + (i - SEG_X - SEG_W);     dst = w_all + (i - SEG_X); }
    else if (i < SEG_X + 3 * SEG_W)   { src = Wv + (i - SEG_X - 2 * SEG_W); dst = w_all + (i - SEG_X); }
    else                              { src = Wo + (i - SEG_X - 3 * SEG_W); dst = wob + (i - SEG_X - 3 * SEG_W); }
    float4 v = *reinterpret_cast<const float4*>(src);
    __hip_bfloat162 lo, hi;
    lo.x = __float2bfloat16(v.x); lo.y = __float2bfloat16(v.y);
    hi.x = __float2bfloat16(v.z); hi.y = __float2bfloat16(v.w);
    __hip_bfloat162* d2 = reinterpret_cast<__hip_bfloat162*>(dst);
    d2[0] = lo; d2[1] = hi;
}

// ---------------------------------------------------------------------------
// 256x256-tile, 16-wave (1024-thread), BK=64 deep-pipelined GEMM (T2+T3+T4+T5).
//   - ROUNDS 1-3 LESSON: with 8 waves (512 thr) the per-wave live set is
//     acc[8][4]=128 + frags ~48 + addr ~25 = ~200 regs, but the allocator
//     pinned the budget at 128 under every occupancy declaration tried
//     ((512,2), (512,1), amdgpu_waves_per_eu(2,2)) -> ~46 regs spilled per
//     K-tile = 289 MB scratch writes/dispatch, MfmaUtil 6%.  Fix: 16 waves,
//     each owning 64x64 -> acc[4][4]=64 + af[4]=16 + b0/b1=16 ~= 116 regs,
//     which fits the 128 budget (proven by the round-0 kernel's clean run).
//     4 waves/EU is also the physical occupancy (1 block/CU @ 128 KiB LDS),
//     so declaration and reality agree.
//   - 4 phases per K-tile (k-half x col-pair); stage-unit order A-k0, B-k0,
//     A-k1, B-k1; one unit (= 1 gload16/thread, 16 KB) issued per phase;
//     counted s_waitcnt vmcnt(2) at end of P1 and P3 only (never 0 in loop).
//   - LDS: linear global_load_lds dest, involutive XOR source/read swizzle
//     chunk c = lq ^ ((r>>1)&3) -> 2-way (free) bank access on ds_read_b128.
//   - raw s_barrier + lgkmcnt(0) + sched_barrier(0) + setprio around each
//     8-MFMA cluster.
// IS_PROJ: fused RoPE (Q prescaled) -> qkb, V transposed -> vtb.
// else:    plain fp32 C store (output projection).
// ---------------------------------------------------------------------------
#define PHASE_SYNC()                                          \
    __builtin_amdgcn_s_barrier();                             \
    asm volatile("s_waitcnt lgkmcnt(0)" ::: "memory");        \
    __builtin_amdgcn_sched_barrier(0)

#define CLUSTER(B2, CB)                                                                                         \
    do {                                                                                                        \
        __builtin_amdgcn_s_setprio(1);                                                                          \
        if (isV) {                                                                                              \
            _Pragma("unroll")                                                                                   \
            for (int mt = 0; mt < 4; ++mt) {                                                                    \
                acc[mt][CB]     = __builtin_amdgcn_mfma_f32_16x16x32_bf16(B2[0], af[mt], acc[mt][CB], 0, 0, 0); \
                acc[mt][CB + 1] = __builtin_amdgcn_mfma_f32_16x16x32_bf16(B2[1], af[mt], acc[mt][CB + 1], 0, 0, 0); \
            }                                                                                                   \
        } else {                                                                                                \
            _Pragma("unroll")                                                                                   \
            for (int mt = 0; mt < 4; ++mt) {                                                                    \
                acc[mt][CB]     = __builtin_amdgcn_mfma_f32_16x16x32_bf16(af[mt], B2[0], acc[mt][CB], 0, 0, 0); \
                acc[mt][CB + 1] = __builtin_amdgcn_mfma_f32_16x16x32_bf16(af[mt], B2[1], acc[mt][CB + 1], 0, 0, 0); \
            }                                                                                                   \
        }                                                                                                       \
        __builtin_amdgcn_s_setprio(0);                                                                          \
    } while (0)

template <bool IS_PROJ>
__global__ __launch_bounds__(1024, 1) void gemm256_kernel(
    const bf16* __restrict__ A, const bf16* __restrict__ W,
    bf16* __restrict__ qkb, bf16* __restrict__ vtb,
    float* __restrict__ C, const int* __restrict__ pos)
{
    // [dbuf][k-half][256 rows x 32 k], row stride 32 bf16 = 64B
    __shared__ bf16 As[2][2][256 * 32];
    __shared__ bf16 Bs[2][2][256 * 32];

    const int tileM = blockIdx.x * 256;
    const int tileN = blockIdx.y * 256;
    const int tid = threadIdx.x;
    const int w = tid >> 6, lane = tid & 63;
    const int wm = w >> 2, wn = w & 3;          // 4 M-waves x 4 N-waves
    const int l15 = lane & 15, lq = lane >> 4;
    const bool isV = IS_PROJ && (tileN >= 2048);

    floatx4 acc[4][4];
    #pragma unroll
    for (int a = 0; a < 4; ++a)
        #pragma unroll
        for (int b = 0; b < 4; ++b)
            acc[a][b] = (floatx4){0.f, 0.f, 0.f, 0.f};

    // --- staging: one k-half unit = 256 rows x 32 k = 16KB = 1 gload16/thread
    // granule g = tid; r = g>>2; stored chunk g&3 holds global k-chunk
    // (g&3) ^ ((r>>1)&3)   (involutive XOR swizzle, rule #21)
    const int srow = tid >> 2;
    const int schunk = ((tid & 3) ^ ((srow >> 1) & 3)) * 8;
    auto stageA = [&](int buf, int kh, int kb) {
        gload16(A + (size_t)(tileM + srow) * KDIM + kb + kh * 32 + schunk,
                &As[buf][kh][(size_t)(tid >> 6) * 512]);
    };
    auto stageB = [&](int buf, int kh, int kb) {
        gload16(W + (size_t)(tileN + srow) * KDIM + kb + kh * 32 + schunk,
                &Bs[buf][kh][(size_t)(tid >> 6) * 512]);
    };

    // --- fragment reads: lane wants global k-chunk lq of its row
    auto LDA = [&](int buf, int ks, int mt) -> short8 {
        const int r = wm * 64 + mt * 16 + l15;
        const int c = lq ^ ((r >> 1) & 3);
        return *reinterpret_cast<const short8*>(&As[buf][ks][r * 32 + c * 8]);
    };
    auto LDB = [&](int buf, int ks, int nt) -> short8 {
        const int r = wn * 64 + nt * 16 + l15;
        const int c = lq ^ ((r >> 1) & 3);
        return *reinterpret_cast<const short8*>(&Bs[buf][ks][r * 32 + c * 8]);
    };

    // --- prologue: fully stage K-tile 0 into buf 0, drain once
    stageA(0, 0, 0); stageB(0, 0, 0); stageA(0, 1, 0); stageB(0, 1, 0);
    asm volatile("s_waitcnt vmcnt(0)" ::: "memory");
    __builtin_amdgcn_s_barrier();

    short8 af[4], b0[2], b1[2];
    const int NT = KDIM / 64;  // 16 K-tiles

    for (int t = 0; t < NT - 1; ++t) {
        const int cur = t & 1, nxt = cur ^ 1, kn = (t + 1) * 64;

        // P0: ks0, cols 0-1; issue unit (t+1).A-k0
        #pragma unroll
        for (int mt = 0; mt < 4; ++mt) af[mt] = LDA(cur, 0, mt);
        b0[0] = LDB(cur, 0, 0); b0[1] = LDB(cur, 0, 1);
        stageA(nxt, 0, kn);
        PHASE_SYNC();
        CLUSTER(b0, 0);
        __builtin_amdgcn_s_barrier();

        // P1: ks0, cols 2-3; issue (t+1).B-k0; wait old A-k1/B-k1 landed
        b1[0] = LDB(cur, 0, 2); b1[1] = LDB(cur, 0, 3);
        stageB(nxt, 0, kn);
        PHASE_SYNC();
        CLUSTER(b1, 2);
        asm volatile("s_waitcnt vmcnt(2)" ::: "memory");
        __builtin_amdgcn_s_barrier();

        // P2: ks1, cols 0-1; issue (t+1).A-k1
        #pragma unroll
        for (int mt = 0; mt < 4; ++mt) af[mt] = LDA(cur, 1, mt);
        b0[0] = LDB(cur, 1, 0); b0[1] = LDB(cur, 1, 1);
        stageA(nxt, 1, kn);
        PHASE_SYNC();
        CLUSTER(b0, 0);
        __builtin_amdgcn_s_barrier();

        // P3: ks1, cols 2-3; issue (t+1).B-k1; wait next A-k0/B-k0 landed
        b1[0] = LDB(cur, 1, 2); b1[1] = LDB(cur, 1, 3);
        stageB(nxt, 1, kn);
        PHASE_SYNC();
        CLUSTER(b1, 2);
        asm volatile("s_waitcnt vmcnt(2)" ::: "memory");
        __builtin_amdgcn_s_barrier();
    }

    // --- peeled last K-tile (no staging; in-flight = {A-k1, B-k1} = 2 loads)
    {
        const int cur = (NT - 1) & 1;
        #pragma unroll
        for (int mt = 0; mt < 4; ++mt) af[mt] = LDA(cur, 0, mt);
        b0[0] = LDB(cur, 0, 0); b0[1] = LDB(cur, 0, 1);
        PHASE_SYNC();
        CLUSTER(b0, 0);
        __builtin_amdgcn_s_barrier();

        b1[0] = LDB(cur, 0, 2); b1[1] = LDB(cur, 0, 3);
        PHASE_SYNC();
        CLUSTER(b1, 2);
        asm volatile("s_waitcnt vmcnt(0)" ::: "memory");
        __builtin_amdgcn_s_barrier();

        #pragma unroll
        for (int mt = 0; mt < 4; ++mt) af[mt] = LDA(cur, 1, mt);
        b0[0] = LDB(cur, 1, 0); b0[1] = LDB(cur, 1, 1);
        PHASE_SYNC();
        CLUSTER(b0, 0);
        __builtin_amdgcn_s_barrier();

        b1[0] = LDB(cur, 1, 2); b1[1] = LDB(cur, 1, 3);
        PHASE_SYNC();
        CLUSTER(b1, 2);
    }

    // --- epilogues (C/D layout: col = l15, row = lq*4 + reg)
    if (!IS_PROJ) {
        #pragma unroll
        for (int mt = 0; mt < 4; ++mt) {
            #pragma unroll
            for (int nt = 0; nt < 4; ++nt) {
                const int col = tileN + wn * 64 + nt * 16 + l15;
                #pragma unroll
                for (int r = 0; r < 4; ++r) {
                    const int row = tileM + wm * 64 + mt * 16 + lq * 4 + r;
                    C[(size_t)row * D_MODEL + col] = acc[mt][nt][r];
                }
            }
        }
    } else if (!isV) {
        const float qscale = (tileN < 1024) ? QSCALE : 1.0f;
        const int p64 = (pos[1] == 0);
        #pragma unroll
        for (int mt = 0; mt < 4; ++mt) {
            #pragma unroll
            for (int nt = 0; nt < 4; ++nt) {
                const int colg = tileN + wn * 64 + nt * 16 + l15;
                const int ip = (colg & 63) >> 1;
                const float freq = __expf((float)(2 * ip) * ROPE_C);
                #pragma unroll
                for (int r = 0; r < 4; ++r) {
                    const int row = tileM + wm * 64 + mt * 16 + lq * 4 + r;
                    const int s = row & (SEQ - 1);
                    const int ptok = p64 ? pos[2 * s] : pos[s];
                    const float v = acc[mt][nt][r];
                    const float pv = __shfl_xor(v, 1);
                    const float ang = (float)ptok * freq;
                    const float sn = __sinf(ang), cs = __cosf(ang);
                    const float outv = ((colg & 1) ? fmaf(pv, sn, v * cs)
                                                   : (v * cs - pv * sn)) * qscale;
                    qkb[(size_t)row * QKSTRIDE + colg] = __float2bfloat16(outv);
                }
            }
        }
    } else {
        // swapped-operand V tile: reg index = N (v-col), l15 = M (seq row)
        const int bq = tileM >> 11;
        const int tnoff = tileN - 2048;
        #pragma unroll
        for (int mt = 0; mt < 4; ++mt) {
            const int s = (tileM & (SEQ - 1)) + wm * 64 + mt * 16 + l15;
            #pragma unroll
            for (int nt = 0; nt < 4; ++nt) {
                #pragma unroll
                for (int r = 0; r < 4; ++r) {
                    const int vcol = tnoff + wn * 64 + nt * 16 + lq * 4 + r;
                    const int bh = bq * 16 + (vcol >> 6);
                    const int d = vcol & 63;
                    vtb[((size_t)bh * 64 + d) * SEQ + s] =
                        __float2bfloat16(acc[mt][nt][r]);
                }
            }
        }
    }
}

// ---------------------------------------------------------------------------
// MFMA flash attention: paired q-tiles (load-balanced: every block = 33
// tile-units), max-free softmax (Q pre-scaled to log2 domain, P = exp2(S)
// via __builtin_amdgcn_exp2f), l computed via MFMA against an all-ones B
// fragment (replicated per lane, no epilogue reduction), double-buffered
// K/V prefetch, Ps stride 32 with chunk^=(row>>2) swizzle.
// ---------------------------------------------------------------------------
__global__ __launch_bounds__(256) void flash_attn_kernel(
    const bf16* __restrict__ qk, const bf16* __restrict__ vtb,
    bf16* __restrict__ O)
{
    __shared__ bf16 Ks[2][2][64][32];      // [buf][panel][row][32]
    __shared__ bf16 Vt[2][2][64][32];
    __shared__ bf16 Ps[4][2][16][32];      // [wave][kp][row][32], swizzled

    const int qtA = blockIdx.x;          // 0..15
    const int qtB = 31 - blockIdx.x;     // 31..16
    const int bh = blockIdx.y;
    const int b = bh >> 4, h = bh & 15;
    const int t = threadIdx.x;
    const int w = t >> 6, lane = t & 63;
    const int l15 = lane & 15, lq = lane >> 4;

    const bf16* qbase = qk + (size_t)b * SEQ * QKSTRIDE + h * 64;
    const bf16* kbase = qbase + 1024;
    const bf16* vbase = vtb + (size_t)bh * 64 * SEQ;

    short8 aqA[2], aqB[2];
    {
        const bf16* qr = qbase + (size_t)(qtA * 64 + 16 * w + l15) * QKSTRIDE;
        aqA[0] = *reinterpret_cast<const short8*>(qr + lq * 8);
        aqA[1] = *reinterpret_cast<const short8*>(qr + 32 + lq * 8);
        qr = qbase + (size_t)(qtB * 64 + 16 * w + l15) * QKSTRIDE;
        aqB[0] = *reinterpret_cast<const short8*>(qr + lq * 8);
        aqB[1] = *reinterpret_cast<const short8*>(qr + 32 + lq * 8);
    }

    const int srow = lane >> 2;
    const int scol = (((lane & 3) ^ (srow & 3))) * 8;   // staging swizzle
    const int rsw = lq ^ (l15 & 3);                     // K/V frag read chunk
    const int psw = lq ^ (l15 >> 2);                    // Ps frag read chunk

    const short8 ones8 = {0x3F80, 0x3F80, 0x3F80, 0x3F80,
                          0x3F80, 0x3F80, 0x3F80, 0x3F80};  // bf16 1.0 x8

    floatx4 accA[4], accB[4], lAcc[2];
    #pragma unroll
    for (int nt = 0; nt < 4; ++nt) {
        accA[nt] = (floatx4){0.f, 0.f, 0.f, 0.f};
        accB[nt] = (floatx4){0.f, 0.f, 0.f, 0.f};
    }
    lAcc[0] = (floatx4){0.f, 0.f, 0.f, 0.f};
    lAcc[1] = (floatx4){0.f, 0.f, 0.f, 0.f};

    const int rowloc = 16 * w + lq * 4;

    // max-free softmax + PV + MFMA-l for one q-tile
    auto softmax_pv = [&](floatx4* accS, floatx4* accO, floatx4& accL,
                          bool diag, int cur) {
        #pragma unroll
        for (int nt = 0; nt < 4; ++nt) {
            const int colloc = nt * 16 + l15;
            #pragma unroll
            for (int r = 0; r < 4; ++r) {
                float e = __builtin_amdgcn_exp2f(accS[nt][r]);
                if (diag && colloc > rowloc + r) e = 0.f;
                // store: row = lq*4+r (row>>2 == lq), col = (nt&1)*16 + l15
                // chunk = (nt&1)*2 + (l15>>3), swizzled ^= lq
                Ps[w][nt >> 1][lq * 4 + r]
                  [((((nt & 1) * 2 + (l15 >> 3)) ^ lq) * 8) + (l15 & 7)] =
                    __float2bfloat16(e);
            }
        }
        #pragma unroll
        for (int kp = 0; kp < 2; ++kp) {
            const short8 ap = *reinterpret_cast<const short8*>(
                &Ps[w][kp][l15][psw * 8]);
            #pragma unroll
            for (int nt = 0; nt < 4; ++nt) {
                const short8 bv = *reinterpret_cast<const short8*>(
                    &Vt[cur][kp][nt * 16 + l15][rsw * 8]);
                accO[nt] = __builtin_amdgcn_mfma_f32_16x16x32_bf16(
                    ap, bv, accO[nt], 0, 0, 0);
            }
            accL = __builtin_amdgcn_mfma_f32_16x16x32_bf16(
                ap, ones8, accL, 0, 0, 0);
        }
    };

    auto stage = [&](int kt, int buf) {
        #pragma unroll
        for (int p = 0; p < 2; ++p) {
            gload16(kbase + (size_t)(kt * 64 + 16 * w + srow) * QKSTRIDE
                        + p * 32 + scol,
                    &Ks[buf][p][16 * w][0]);
            gload16(vbase + (size_t)(16 * w + srow) * SEQ + kt * 64
                        + p * 32 + scol,
                    &Vt[buf][p][16 * w][0]);
        }
    };

    stage(0, 0);
    __syncthreads();

    for (int kt = 0; kt <= qtB; ++kt) {
        const int cur = kt & 1, nxt = cur ^ 1;
        if (kt < qtB) stage(kt + 1, nxt);

        short8 bk[2][4];
        #pragma unroll
        for (int p = 0; p < 2; ++p)
            #pragma unroll
            for (int nt = 0; nt < 4; ++nt)
                bk[p][nt] = *reinterpret_cast<const short8*>(
                    &Ks[cur][p][nt * 16 + l15][rsw * 8]);

        floatx4 sB[4];
        #pragma unroll
        for (int nt = 0; nt < 4; ++nt) sB[nt] = (floatx4){0.f, 0.f, 0.f, 0.f};
        #pragma unroll
        for (int p = 0; p < 2; ++p)
            #pragma unroll
            for (int nt = 0; nt < 4; ++nt)
                sB[nt] = __builtin_amdgcn_mfma_f32_16x16x32_bf16(
                    aqB[p], bk[p][nt], sB[nt], 0, 0, 0);

        if (kt <= qtA) {
            floatx4 sA[4];
            #pragma unroll
            for (int nt = 0; nt < 4; ++nt) sA[nt] = (floatx4){0.f, 0.f, 0.f, 0.f};
            #pragma unroll
            for (int p = 0; p < 2; ++p)
                #pragma unroll
                for (int nt = 0; nt < 4; ++nt)
                    sA[nt] = __builtin_amdgcn_mfma_f32_16x16x32_bf16(
                        aqA[p], bk[p][nt], sA[nt], 0, 0, 0);
            softmax_pv(sB, accB, lAcc[1], kt == qtB, cur);
            softmax_pv(sA, accA, lAcc[0], kt == qtA, cur);
        } else {
            softmax_pv(sB, accB, lAcc[1], kt == qtB, cur);
        }
        __syncthreads();
    }

    // Epilogue: accL already holds the row sums (replicated across l15).
    auto epilogue = [&](floatx4* accO, floatx4& accL, int qt) {
        #pragma unroll
        for (int r = 0; r < 4; ++r) {
            const float inv = 1.f / accL[r];
            const int qrow = qt * 64 + 16 * w + lq * 4 + r;
            #pragma unroll
            for (int nt = 0; nt < 4; ++nt) {
                O[((size_t)(b * SEQ + qrow)) * D_MODEL + h * DK + nt * 16 + l15] =
                    __float2bfloat16(accO[nt][r] * inv);
            }
        }
    };
    epilogue(accA, lAcc[0], qtA);
    epilogue(accB, lAcc[1], qtB);
}

extern "C" void kernel_launch(void* const* d_in, const int* in_sizes, int n_in,
                              void* d_out, int out_size, void* d_ws, size_t ws_size,
                              hipStream_t stream)
{
    const float* x   = (const float*)d_in[0];
    const int*   pos = (const int*)d_in[1];
    const float* Wq  = (const float*)d_in[2];
    const float* Wk  = (const float*)d_in[3];
    const float* Wv  = (const float*)d_in[4];
    const float* Wo  = (const float*)d_in[5];
    float* out = (float*)d_out;

    bf16* xb    = (bf16*)d_ws;
    bf16* w_all = xb + SEG_X;
    bf16* wob   = w_all + 3 * SEG_W;
    bf16* qkb   = wob + SEG_W;                     // 4096 x 2048 (Q|K roped)
    bf16* vtb   = qkb + (size_t)MROWS * QKSTRIDE;  // 32 bh x 64 d x 2048 s
    bf16* ob    = xb;                              // reuse: x dead after GEMM1

    cast_kernel<<<8192, 256, 0, stream>>>(x, Wq, Wk, Wv, Wo, xb, w_all, wob);
    gemm256_kernel<true><<<dim3(16, 12), 1024, 0, stream>>>(
        xb, w_all, qkb, vtb, nullptr, pos);
    flash_attn_kernel<<<dim3(16, 32), 256, 0, stream>>>(qkb, vtb, ob);
    gemm256_kernel<false><<<dim3(16, 4), 1024, 0, stream>>>(
        ob, wob, nullptr, nullptr, out, nullptr);
}

// Round 5
// 201.757 us; speedup vs baseline: 1.5942x; 1.5942x over previous
//
#include <hip/hip_runtime.h>
#include <hip/hip_bf16.h>
#include <math.h>

typedef __hip_bfloat16 bf16;
typedef __attribute__((ext_vector_type(8))) short short8;
typedef __attribute__((ext_vector_type(4))) float floatx4;

#define D_MODEL 1024
#define NUM_HEADS 16
#define DK 64
#define SEQ 2048
#define BATCH 2
#define MROWS (BATCH * SEQ)          // 4096
#define KDIM 1024
#define SEG_X ((size_t)MROWS * D_MODEL)      // 4194304
#define SEG_W ((size_t)D_MODEL * D_MODEL)    // 1048576
#define QKSTRIDE 2048                         // fused Q|K row stride
#define ROPE_C (-9.2103403719761836f / 64.f)  // -ln(10000)/dk
// Q prescale: dk^-0.5 * log2(e)  -> scores arrive in log2 domain, P = exp2(S)
#define QSCALE (0.125f * 1.4426950408889634f)

__device__ inline void gload16(const void* g, void* l) {
    __builtin_amdgcn_global_load_lds(
        (const __attribute__((address_space(1))) void*)g,
        (__attribute__((address_space(3))) void*)l, 16, 0, 0);
}

// ---------------------------------------------------------------------------
// Cast fp32 inputs to bf16 workspace buffers.
// ---------------------------------------------------------------------------
__global__ __launch_bounds__(256) void cast_kernel(
    const float* __restrict__ x,  const float* __restrict__ Wq,
    const float* __restrict__ Wk, const float* __restrict__ Wv,
    const float* __restrict__ Wo,
    bf16* __restrict__ xb, bf16* __restrict__ w_all, bf16* __restrict__ wob)
{
    const size_t i = ((size_t)blockIdx.x * 256 + threadIdx.x) * 4;
    const float* src; bf16* dst;
    if (i < SEG_X)                    { src = x  + i;                       dst = xb + i; }
    else if (i < SEG_X + SEG_W)       { src = Wq + (i - SEG_X);             dst = w_all + (i - SEG_X); }
    else if (i < SEG_X + 2 * SEG_W)   { src = Wk + (i - SEG_X - SEG_W);     dst = w_all + (i - SEG_X); }
    else if (i < SEG_X + 3 * SEG_W)   { src = Wv + (i - SEG_X - 2 * SEG_W); dst = w_all + (i - SEG_X); }
    else                              { src = Wo + (i - SEG_X - 3 * SEG_W); dst = wob + (i - SEG_X - 3 * SEG_W); }
    float4 v = *reinterpret_cast<const float4*>(src);
    __hip_bfloat162 lo, hi;
    lo.x = __float2bfloat16(v.x); lo.y = __float2bfloat16(v.y);
    hi.x = __float2bfloat16(v.z); hi.y = __float2bfloat16(v.w);
    __hip_bfloat162* d2 = reinterpret_cast<__hip_bfloat162*>(dst);
    d2[0] = lo; d2[1] = hi;
}

// ---------------------------------------------------------------------------
// GEMM: 128x128 tile, 4 waves (256 thr), BK=64, double-buffered LDS (64 KB),
// T3-minimum 2-phase schedule (catalog recipe), pure HIP / __syncthreads.
//   - ROUNDS 1-4 LESSON: the allocator pins a 128-reg/wave unified budget
//     for >=512-thread / 128KB-LDS / inline-asm configs regardless of
//     __launch_bounds__ or amdgpu_waves_per_eu; any live set >128 regs
//     spills the accumulator (~300 MB scratch writes, MfmaUtil 6%).  This
//     kernel stays in the round-0-proven regime: 256 threads, 64 KB LDS,
//     live set ~116 regs < 128 by construction, no inline asm.
//   - Per K-step: stage NEXT K-tile into buf^1 (8 gload16/thread issued
//     FIRST), then compute current buf (16 ds_read_b128 + 32 MFMA/wave),
//     then one __syncthreads (its vmcnt drain comes ~350+ cycles after
//     load issue -> L2/L3 latency hidden; 2 blocks/CU TLP covers the rest).
//     Round-0's single-buffer drained BEFORE compute = full latency exposed
//     every step (the ~60% stall at MfmaUtil 15%).
//   - LDS swizzle: linear gload_lds dest; source granule g of row r=g>>2
//     holds global k-chunk (g&3)^((r>>1)&3); read chunk lq^((r>>1)&3).
//     This exact pattern measured SQ_LDS_BANK_CONFLICT = 0 in rounds 1-4
//     (round-0's lq^(l15&3) variant left 3.1M conflicts).
// IS_PROJ: fused RoPE (Q prescaled) -> qkb, V transposed -> vtb.
// else:    plain fp32 C store (output projection).
// ---------------------------------------------------------------------------
template <bool IS_PROJ>
__global__ __launch_bounds__(256) void gemm128_kernel(
    const bf16* __restrict__ A, const bf16* __restrict__ W,
    bf16* __restrict__ qkb, bf16* __restrict__ vtb,
    float* __restrict__ C, const int* __restrict__ pos)
{
    // [dbuf][k-half][128 rows x 32 k], row stride 32 bf16 = 64 B
    __shared__ bf16 As[2][2][128 * 32];
    __shared__ bf16 Bs[2][2][128 * 32];

    const int tileM = blockIdx.x * 128;
    const int tileN = blockIdx.y * 128;
    const int tid = threadIdx.x;
    const int w = tid >> 6, lane = tid & 63;
    const int wm = (w & 1) * 64, wn = (w >> 1) * 64;   // 2x2 waves of 64x64
    const int l15 = lane & 15, lq = lane >> 4;
    const bool isV = IS_PROJ && (tileN >= 2048);

    floatx4 acc[4][4];
    #pragma unroll
    for (int a = 0; a < 4; ++a)
        #pragma unroll
        for (int b = 0; b < 4; ++b)
            acc[a][b] = (floatx4){0.f, 0.f, 0.f, 0.f};

    // one K-tile = 128 rows x 64 k per matrix = 16 KB = 4 gload16/thread each
    auto stage = [&](int buf, int kb) {
        #pragma unroll
        for (int kh = 0; kh < 2; ++kh) {
            #pragma unroll
            for (int i = 0; i < 2; ++i) {
                const int g = i * 256 + tid;     // granule 0..511 per k-half
                const int r = g >> 2;            // row 0..127
                const int c = ((g & 3) ^ ((r >> 1) & 3)) * 8;  // swizzled src
                const int dst = (i * 256 + (tid & 0xC0)) * 8;  // linear dest
                gload16(A + (size_t)(tileM + r) * KDIM + kb + kh * 32 + c,
                        &As[buf][kh][dst]);
                gload16(W + (size_t)(tileN + r) * KDIM + kb + kh * 32 + c,
                        &Bs[buf][kh][dst]);
            }
        }
    };

    stage(0, 0);
    __syncthreads();

    const int NT = KDIM / 64;  // 16 K-tiles
    for (int t = 0; t < NT; ++t) {
        const int cur = t & 1;
        if (t + 1 < NT) stage(cur ^ 1, (t + 1) * 64);

        #pragma unroll
        for (int ks = 0; ks < 2; ++ks) {
            short8 af[4], bfr[4];
            #pragma unroll
            for (int mt = 0; mt < 4; ++mt) {
                const int r = wm + mt * 16 + l15;
                af[mt] = *reinterpret_cast<const short8*>(
                    &As[cur][ks][r * 32 + (lq ^ ((r >> 1) & 3)) * 8]);
            }
            #pragma unroll
            for (int nt = 0; nt < 4; ++nt) {
                const int r = wn + nt * 16 + l15;
                bfr[nt] = *reinterpret_cast<const short8*>(
                    &Bs[cur][ks][r * 32 + (lq ^ ((r >> 1) & 3)) * 8]);
            }
            if (isV) {
                #pragma unroll
                for (int mt = 0; mt < 4; ++mt)
                    #pragma unroll
                    for (int nt = 0; nt < 4; ++nt)
                        acc[mt][nt] = __builtin_amdgcn_mfma_f32_16x16x32_bf16(
                            bfr[nt], af[mt], acc[mt][nt], 0, 0, 0);
            } else {
                #pragma unroll
                for (int mt = 0; mt < 4; ++mt)
                    #pragma unroll
                    for (int nt = 0; nt < 4; ++nt)
                        acc[mt][nt] = __builtin_amdgcn_mfma_f32_16x16x32_bf16(
                            af[mt], bfr[nt], acc[mt][nt], 0, 0, 0);
            }
        }
        __syncthreads();
    }

    // --- epilogues (C/D layout: col = l15, row = lq*4 + reg; round-0 proven)
    if (!IS_PROJ) {
        #pragma unroll
        for (int mt = 0; mt < 4; ++mt) {
            #pragma unroll
            for (int nt = 0; nt < 4; ++nt) {
                const int col = tileN + wn + nt * 16 + l15;
                #pragma unroll
                for (int r = 0; r < 4; ++r) {
                    const int row = tileM + wm + mt * 16 + lq * 4 + r;
                    C[(size_t)row * D_MODEL + col] = acc[mt][nt][r];
                }
            }
        }
    } else if (!isV) {
        const float qscale = (tileN < 1024) ? QSCALE : 1.0f;
        const int p64 = (pos[1] == 0);
        #pragma unroll
        for (int mt = 0; mt < 4; ++mt) {
            #pragma unroll
            for (int nt = 0; nt < 4; ++nt) {
                const int colg = tileN + wn + nt * 16 + l15;
                const int ip = (colg & 63) >> 1;
                const float freq = __expf((float)(2 * ip) * ROPE_C);
                #pragma unroll
                for (int r = 0; r < 4; ++r) {
                    const int row = tileM + wm + mt * 16 + lq * 4 + r;
                    const int s = row & (SEQ - 1);
                    const int ptok = p64 ? pos[2 * s] : pos[s];
                    const float v = acc[mt][nt][r];
                    const float pv = __shfl_xor(v, 1);
                    const float ang = (float)ptok * freq;
                    const float sn = __sinf(ang), cs = __cosf(ang);
                    const float outv = ((colg & 1) ? fmaf(pv, sn, v * cs)
                                                   : (v * cs - pv * sn)) * qscale;
                    qkb[(size_t)row * QKSTRIDE + colg] = __float2bfloat16(outv);
                }
            }
        }
    } else {
        // swapped-operand V tile: reg index = N (v-col), l15 = M (seq row)
        const int bq = tileM >> 11;
        const int tnoff = tileN - 2048;
        #pragma unroll
        for (int mt = 0; mt < 4; ++mt) {
            const int s = (tileM & (SEQ - 1)) + wm + mt * 16 + l15;
            #pragma unroll
            for (int nt = 0; nt < 4; ++nt) {
                #pragma unroll
                for (int r = 0; r < 4; ++r) {
                    const int vcol = tnoff + wn + nt * 16 + lq * 4 + r;
                    const int bh = bq * 16 + (vcol >> 6);
                    const int d = vcol & 63;
                    vtb[((size_t)bh * 64 + d) * SEQ + s] =
                        __float2bfloat16(acc[mt][nt][r]);
                }
            }
        }
    }
}

// ---------------------------------------------------------------------------
// MFMA flash attention: paired q-tiles (load-balanced: every block = 33
// tile-units), max-free softmax (Q pre-scaled to log2 domain, P = exp2(S)
// via __builtin_amdgcn_exp2f), l computed via MFMA against an all-ones B
// fragment (replicated per lane, no epilogue reduction), double-buffered
// K/V prefetch, Ps stride 32 with chunk^=(row>>2) swizzle.
// ---------------------------------------------------------------------------
__global__ __launch_bounds__(256) void flash_attn_kernel(
    const bf16* __restrict__ qk, const bf16* __restrict__ vtb,
    bf16* __restrict__ O)
{
    __shared__ bf16 Ks[2][2][64][32];      // [buf][panel][row][32]
    __shared__ bf16 Vt[2][2][64][32];
    __shared__ bf16 Ps[4][2][16][32];      // [wave][kp][row][32], swizzled

    const int qtA = blockIdx.x;          // 0..15
    const int qtB = 31 - blockIdx.x;     // 31..16
    const int bh = blockIdx.y;
    const int b = bh >> 4, h = bh & 15;
    const int t = threadIdx.x;
    const int w = t >> 6, lane = t & 63;
    const int l15 = lane & 15, lq = lane >> 4;

    const bf16* qbase = qk + (size_t)b * SEQ * QKSTRIDE + h * 64;
    const bf16* kbase = qbase + 1024;
    const bf16* vbase = vtb + (size_t)bh * 64 * SEQ;

    short8 aqA[2], aqB[2];
    {
        const bf16* qr = qbase + (size_t)(qtA * 64 + 16 * w + l15) * QKSTRIDE;
        aqA[0] = *reinterpret_cast<const short8*>(qr + lq * 8);
        aqA[1] = *reinterpret_cast<const short8*>(qr + 32 + lq * 8);
        qr = qbase + (size_t)(qtB * 64 + 16 * w + l15) * QKSTRIDE;
        aqB[0] = *reinterpret_cast<const short8*>(qr + lq * 8);
        aqB[1] = *reinterpret_cast<const short8*>(qr + 32 + lq * 8);
    }

    const int srow = lane >> 2;
    const int scol = (((lane & 3) ^ (srow & 3))) * 8;   // staging swizzle
    const int rsw = lq ^ (l15 & 3);                     // K/V frag read chunk
    const int psw = lq ^ (l15 >> 2);                    // Ps frag read chunk

    const short8 ones8 = {0x3F80, 0x3F80, 0x3F80, 0x3F80,
                          0x3F80, 0x3F80, 0x3F80, 0x3F80};  // bf16 1.0 x8

    floatx4 accA[4], accB[4], lAcc[2];
    #pragma unroll
    for (int nt = 0; nt < 4; ++nt) {
        accA[nt] = (floatx4){0.f, 0.f, 0.f, 0.f};
        accB[nt] = (floatx4){0.f, 0.f, 0.f, 0.f};
    }
    lAcc[0] = (floatx4){0.f, 0.f, 0.f, 0.f};
    lAcc[1] = (floatx4){0.f, 0.f, 0.f, 0.f};

    const int rowloc = 16 * w + lq * 4;

    // max-free softmax + PV + MFMA-l for one q-tile
    auto softmax_pv = [&](floatx4* accS, floatx4* accO, floatx4& accL,
                          bool diag, int cur) {
        #pragma unroll
        for (int nt = 0; nt < 4; ++nt) {
            const int colloc = nt * 16 + l15;
            #pragma unroll
            for (int r = 0; r < 4; ++r) {
                float e = __builtin_amdgcn_exp2f(accS[nt][r]);
                if (diag && colloc > rowloc + r) e = 0.f;
                // store: row = lq*4+r (row>>2 == lq), col = (nt&1)*16 + l15
                // chunk = (nt&1)*2 + (l15>>3), swizzled ^= lq
                Ps[w][nt >> 1][lq * 4 + r]
                  [((((nt & 1) * 2 + (l15 >> 3)) ^ lq) * 8) + (l15 & 7)] =
                    __float2bfloat16(e);
            }
        }
        #pragma unroll
        for (int kp = 0; kp < 2; ++kp) {
            const short8 ap = *reinterpret_cast<const short8*>(
                &Ps[w][kp][l15][psw * 8]);
            #pragma unroll
            for (int nt = 0; nt < 4; ++nt) {
                const short8 bv = *reinterpret_cast<const short8*>(
                    &Vt[cur][kp][nt * 16 + l15][rsw * 8]);
                accO[nt] = __builtin_amdgcn_mfma_f32_16x16x32_bf16(
                    ap, bv, accO[nt], 0, 0, 0);
            }
            accL = __builtin_amdgcn_mfma_f32_16x16x32_bf16(
                ap, ones8, accL, 0, 0, 0);
        }
    };

    auto stage = [&](int kt, int buf) {
        #pragma unroll
        for (int p = 0; p < 2; ++p) {
            gload16(kbase + (size_t)(kt * 64 + 16 * w + srow) * QKSTRIDE
                        + p * 32 + scol,
                    &Ks[buf][p][16 * w][0]);
            gload16(vbase + (size_t)(16 * w + srow) * SEQ + kt * 64
                        + p * 32 + scol,
                    &Vt[buf][p][16 * w][0]);
        }
    };

    stage(0, 0);
    __syncthreads();

    for (int kt = 0; kt <= qtB; ++kt) {
        const int cur = kt & 1, nxt = cur ^ 1;
        if (kt < qtB) stage(kt + 1, nxt);

        short8 bk[2][4];
        #pragma unroll
        for (int p = 0; p < 2; ++p)
            #pragma unroll
            for (int nt = 0; nt < 4; ++nt)
                bk[p][nt] = *reinterpret_cast<const short8*>(
                    &Ks[cur][p][nt * 16 + l15][rsw * 8]);

        floatx4 sB[4];
        #pragma unroll
        for (int nt = 0; nt < 4; ++nt) sB[nt] = (floatx4){0.f, 0.f, 0.f, 0.f};
        #pragma unroll
        for (int p = 0; p < 2; ++p)
            #pragma unroll
            for (int nt = 0; nt < 4; ++nt)
                sB[nt] = __builtin_amdgcn_mfma_f32_16x16x32_bf16(
                    aqB[p], bk[p][nt], sB[nt], 0, 0, 0);

        if (kt <= qtA) {
            floatx4 sA[4];
            #pragma unroll
            for (int nt = 0; nt < 4; ++nt) sA[nt] = (floatx4){0.f, 0.f, 0.f, 0.f};
            #pragma unroll
            for (int p = 0; p < 2; ++p)
                #pragma unroll
                for (int nt = 0; nt < 4; ++nt)
                    sA[nt] = __builtin_amdgcn_mfma_f32_16x16x32_bf16(
                        aqA[p], bk[p][nt], sA[nt], 0, 0, 0);
            softmax_pv(sB, accB, lAcc[1], kt == qtB, cur);
            softmax_pv(sA, accA, lAcc[0], kt == qtA, cur);
        } else {
            softmax_pv(sB, accB, lAcc[1], kt == qtB, cur);
        }
        __syncthreads();
    }

    // Epilogue: accL already holds the row sums (replicated across l15).
    auto epilogue = [&](floatx4* accO, floatx4& accL, int qt) {
        #pragma unroll
        for (int r = 0; r < 4; ++r) {
            const float inv = 1.f / accL[r];
            const int qrow = qt * 64 + 16 * w + lq * 4 + r;
            #pragma unroll
            for (int nt = 0; nt < 4; ++nt) {
                O[((size_t)(b * SEQ + qrow)) * D_MODEL + h * DK + nt * 16 + l15] =
                    __float2bfloat16(accO[nt][r] * inv);
            }
        }
    };
    epilogue(accA, lAcc[0], qtA);
    epilogue(accB, lAcc[1], qtB);
}

extern "C" void kernel_launch(void* const* d_in, const int* in_sizes, int n_in,
                              void* d_out, int out_size, void* d_ws, size_t ws_size,
                              hipStream_t stream)
{
    const float* x   = (const float*)d_in[0];
    const int*   pos = (const int*)d_in[1];
    const float* Wq  = (const float*)d_in[2];
    const float* Wk  = (const float*)d_in[3];
    const float* Wv  = (const float*)d_in[4];
    const float* Wo  = (const float*)d_in[5];
    float* out = (float*)d_out;

    bf16* xb    = (bf16*)d_ws;
    bf16* w_all = xb + SEG_X;
    bf16* wob   = w_all + 3 * SEG_W;
    bf16* qkb   = wob + SEG_W;                     // 4096 x 2048 (Q|K roped)
    bf16* vtb   = qkb + (size_t)MROWS * QKSTRIDE;  // 32 bh x 64 d x 2048 s
    bf16* ob    = xb;                              // reuse: x dead after GEMM1

    cast_kernel<<<8192, 256, 0, stream>>>(x, Wq, Wk, Wv, Wo, xb, w_all, wob);
    gemm128_kernel<true><<<dim3(32, 24), 256, 0, stream>>>(
        xb, w_all, qkb, vtb, nullptr, pos);
    flash_attn_kernel<<<dim3(16, 32), 256, 0, stream>>>(qkb, vtb, ob);
    gemm128_kernel<false><<<dim3(32, 8), 256, 0, stream>>>(
        ob, wob, nullptr, nullptr, out, nullptr);
}

// Round 6
// 194.522 us; speedup vs baseline: 1.6535x; 1.0372x over previous
//
#include <hip/hip_runtime.h>
#include <hip/hip_bf16.h>
#include <math.h>

typedef __hip_bfloat16 bf16;
typedef __attribute__((ext_vector_type(8))) short short8;
typedef __attribute__((ext_vector_type(4))) float floatx4;

#define D_MODEL 1024
#define NUM_HEADS 16
#define DK 64
#define SEQ 2048
#define BATCH 2
#define MROWS (BATCH * SEQ)          // 4096
#define KDIM 1024
#define SEG_X ((size_t)MROWS * D_MODEL)      // 4194304
#define SEG_W ((size_t)D_MODEL * D_MODEL)    // 1048576
#define QKSTRIDE 2048                         // fused Q|K row stride
#define ROPE_C (-9.2103403719761836f / 64.f)  // -ln(10000)/dk
// Q prescale: dk^-0.5 * log2(e)  -> scores arrive in log2 domain, P = exp2(S)
#define QSCALE (0.125f * 1.4426950408889634f)

__device__ inline void gload16(const void* g, void* l) {
    __builtin_amdgcn_global_load_lds(
        (const __attribute__((address_space(1))) void*)g,
        (__attribute__((address_space(3))) void*)l, 16, 0, 0);
}

// ---------------------------------------------------------------------------
// Cast fp32 inputs to bf16 workspace buffers.
// ---------------------------------------------------------------------------
__global__ __launch_bounds__(256) void cast_kernel(
    const float* __restrict__ x,  const float* __restrict__ Wq,
    const float* __restrict__ Wk, const float* __restrict__ Wv,
    const float* __restrict__ Wo,
    bf16* __restrict__ xb, bf16* __restrict__ w_all, bf16* __restrict__ wob)
{
    const size_t i = ((size_t)blockIdx.x * 256 + threadIdx.x) * 4;
    const float* src; bf16* dst;
    if (i < SEG_X)                    { src = x  + i;                       dst = xb + i; }
    else if (i < SEG_X + SEG_W)       { src = Wq + (i - SEG_X);             dst = w_all + (i - SEG_X); }
    else if (i < SEG_X + 2 * SEG_W)   { src = Wk + (i - SEG_X - SEG_W);     dst = w_all + (i - SEG_X); }
    else if (i < SEG_X + 3 * SEG_W)   { src = Wv + (i - SEG_X - 2 * SEG_W); dst = w_all + (i - SEG_X); }
    else                              { src = Wo + (i - SEG_X - 3 * SEG_W); dst = wob + (i - SEG_X - 3 * SEG_W); }
    float4 v = *reinterpret_cast<const float4*>(src);
    __hip_bfloat162 lo, hi;
    lo.x = __float2bfloat16(v.x); lo.y = __float2bfloat16(v.y);
    hi.x = __float2bfloat16(v.z); hi.y = __float2bfloat16(v.w);
    __hip_bfloat162* d2 = reinterpret_cast<__hip_bfloat162*>(dst);
    d2[0] = lo; d2[1] = hi;
}

// ---------------------------------------------------------------------------
// GEMM: 128x128 tile, 4 waves (256 thr), BK=64, double-buffered LDS (64 KB),
// T3-minimum 2-phase schedule, pure HIP / __syncthreads.  (Round-5 verified:
// beat baseline; WRITE_SIZE clean, conflicts 0, live set <128 regs.)
// IS_PROJ: fused RoPE (Q prescaled) -> qkb, V transposed -> vtb.
// else:    plain fp32 C store (output projection).
// ---------------------------------------------------------------------------
template <bool IS_PROJ>
__global__ __launch_bounds__(256) void gemm128_kernel(
    const bf16* __restrict__ A, const bf16* __restrict__ W,
    bf16* __restrict__ qkb, bf16* __restrict__ vtb,
    float* __restrict__ C, const int* __restrict__ pos)
{
    // [dbuf][k-half][128 rows x 32 k], row stride 32 bf16 = 64 B
    __shared__ bf16 As[2][2][128 * 32];
    __shared__ bf16 Bs[2][2][128 * 32];

    const int tileM = blockIdx.x * 128;
    const int tileN = blockIdx.y * 128;
    const int tid = threadIdx.x;
    const int w = tid >> 6, lane = tid & 63;
    const int wm = (w & 1) * 64, wn = (w >> 1) * 64;   // 2x2 waves of 64x64
    const int l15 = lane & 15, lq = lane >> 4;
    const bool isV = IS_PROJ && (tileN >= 2048);

    floatx4 acc[4][4];
    #pragma unroll
    for (int a = 0; a < 4; ++a)
        #pragma unroll
        for (int b = 0; b < 4; ++b)
            acc[a][b] = (floatx4){0.f, 0.f, 0.f, 0.f};

    // one K-tile = 128 rows x 64 k per matrix = 16 KB = 4 gload16/thread each
    auto stage = [&](int buf, int kb) {
        #pragma unroll
        for (int kh = 0; kh < 2; ++kh) {
            #pragma unroll
            for (int i = 0; i < 2; ++i) {
                const int g = i * 256 + tid;     // granule 0..511 per k-half
                const int r = g >> 2;            // row 0..127
                const int c = ((g & 3) ^ ((r >> 1) & 3)) * 8;  // swizzled src
                const int dst = (i * 256 + (tid & 0xC0)) * 8;  // linear dest
                gload16(A + (size_t)(tileM + r) * KDIM + kb + kh * 32 + c,
                        &As[buf][kh][dst]);
                gload16(W + (size_t)(tileN + r) * KDIM + kb + kh * 32 + c,
                        &Bs[buf][kh][dst]);
            }
        }
    };

    stage(0, 0);
    __syncthreads();

    const int NT = KDIM / 64;  // 16 K-tiles
    for (int t = 0; t < NT; ++t) {
        const int cur = t & 1;
        if (t + 1 < NT) stage(cur ^ 1, (t + 1) * 64);

        #pragma unroll
        for (int ks = 0; ks < 2; ++ks) {
            short8 af[4], bfr[4];
            #pragma unroll
            for (int mt = 0; mt < 4; ++mt) {
                const int r = wm + mt * 16 + l15;
                af[mt] = *reinterpret_cast<const short8*>(
                    &As[cur][ks][r * 32 + (lq ^ ((r >> 1) & 3)) * 8]);
            }
            #pragma unroll
            for (int nt = 0; nt < 4; ++nt) {
                const int r = wn + nt * 16 + l15;
                bfr[nt] = *reinterpret_cast<const short8*>(
                    &Bs[cur][ks][r * 32 + (lq ^ ((r >> 1) & 3)) * 8]);
            }
            if (isV) {
                #pragma unroll
                for (int mt = 0; mt < 4; ++mt)
                    #pragma unroll
                    for (int nt = 0; nt < 4; ++nt)
                        acc[mt][nt] = __builtin_amdgcn_mfma_f32_16x16x32_bf16(
                            bfr[nt], af[mt], acc[mt][nt], 0, 0, 0);
            } else {
                #pragma unroll
                for (int mt = 0; mt < 4; ++mt)
                    #pragma unroll
                    for (int nt = 0; nt < 4; ++nt)
                        acc[mt][nt] = __builtin_amdgcn_mfma_f32_16x16x32_bf16(
                            af[mt], bfr[nt], acc[mt][nt], 0, 0, 0);
            }
        }
        __syncthreads();
    }

    // --- epilogues (C/D layout: col = l15, row = lq*4 + reg)
    if (!IS_PROJ) {
        #pragma unroll
        for (int mt = 0; mt < 4; ++mt) {
            #pragma unroll
            for (int nt = 0; nt < 4; ++nt) {
                const int col = tileN + wn + nt * 16 + l15;
                #pragma unroll
                for (int r = 0; r < 4; ++r) {
                    const int row = tileM + wm + mt * 16 + lq * 4 + r;
                    C[(size_t)row * D_MODEL + col] = acc[mt][nt][r];
                }
            }
        }
    } else if (!isV) {
        const float qscale = (tileN < 1024) ? QSCALE : 1.0f;
        const int p64 = (pos[1] == 0);
        #pragma unroll
        for (int mt = 0; mt < 4; ++mt) {
            #pragma unroll
            for (int nt = 0; nt < 4; ++nt) {
                const int colg = tileN + wn + nt * 16 + l15;
                const int ip = (colg & 63) >> 1;
                const float freq = __expf((float)(2 * ip) * ROPE_C);
                #pragma unroll
                for (int r = 0; r < 4; ++r) {
                    const int row = tileM + wm + mt * 16 + lq * 4 + r;
                    const int s = row & (SEQ - 1);
                    const int ptok = p64 ? pos[2 * s] : pos[s];
                    const float v = acc[mt][nt][r];
                    const float pv = __shfl_xor(v, 1);
                    const float ang = (float)ptok * freq;
                    const float sn = __sinf(ang), cs = __cosf(ang);
                    const float outv = ((colg & 1) ? fmaf(pv, sn, v * cs)
                                                   : (v * cs - pv * sn)) * qscale;
                    qkb[(size_t)row * QKSTRIDE + colg] = __float2bfloat16(outv);
                }
            }
        }
    } else {
        // swapped-operand V tile: reg index = N (v-col), l15 = M (seq row)
        const int bq = tileM >> 11;
        const int tnoff = tileN - 2048;
        #pragma unroll
        for (int mt = 0; mt < 4; ++mt) {
            const int s = (tileM & (SEQ - 1)) + wm + mt * 16 + l15;
            #pragma unroll
            for (int nt = 0; nt < 4; ++nt) {
                #pragma unroll
                for (int r = 0; r < 4; ++r) {
                    const int vcol = tnoff + wn + nt * 16 + lq * 4 + r;
                    const int bh = bq * 16 + (vcol >> 6);
                    const int d = vcol & 63;
                    vtb[((size_t)bh * 64 + d) * SEQ + s] =
                        __float2bfloat16(acc[mt][nt][r]);
                }
            }
        }
    }
}

// ---------------------------------------------------------------------------
// MFMA flash attention: paired q-tiles (33 tile-units/block, balanced),
// max-free softmax (log2-domain scores, P = exp2), l via MFMA vs all-ones.
// ROUND-6 CHANGES (counter-driven):
//  (1) Ps row stride 32 -> 40 elems (80 B).  At 64 B stride the ds_write_b16
//      had all 64 lanes in 16 dwords (q=lq*4+r rows 256 B apart = 0 mod bank
//      period) -> 4-way conflict; 5.9M cycles matched m136's 3.4cy/store.
//      At 80 B: bank = {lq0, (nt&1)^lq1, h^lq0, pos} -> 32 distinct dwords,
//      2 lanes/dword = free.  Chunk swizzle math UNCHANGED.
//  (2) XCD-aware remap: bh = (lin&7) + 8*((lin>>3)&3), pair = lin>>5 ->
//      each XCD owns 4 whole bh (3 MB K/V/Q < 4 MB L2); per-kt staging
//      drain becomes L2-hit instead of HBM (~900cy -> ~200cy).
//  (3) T5 setprio(1/0) around QK^T and PV MFMA clusters (m191: +4-7% attn).
// ---------------------------------------------------------------------------
__global__ __launch_bounds__(256) void flash_attn_kernel(
    const bf16* __restrict__ qk, const bf16* __restrict__ vtb,
    bf16* __restrict__ O)
{
    __shared__ bf16 Ks[2][2][64][32];      // [buf][panel][row][32]
    __shared__ bf16 Vt[2][2][64][32];
    __shared__ bf16 Ps[4][2][16][40];      // [wave][kp][row][40-pad], swizzled

    const int lin = blockIdx.y * 16 + blockIdx.x;          // 0..511
    const int bh  = (lin & 7) + 8 * ((lin >> 3) & 3);      // 4 bh per XCD
    const int qtA = lin >> 5;            // 0..15
    const int qtB = 31 - qtA;            // 31..16
    const int b = bh >> 4, h = bh & 15;
    const int t = threadIdx.x;
    const int w = t >> 6, lane = t & 63;
    const int l15 = lane & 15, lq = lane >> 4;

    const bf16* qbase = qk + (size_t)b * SEQ * QKSTRIDE + h * 64;
    const bf16* kbase = qbase + 1024;
    const bf16* vbase = vtb + (size_t)bh * 64 * SEQ;

    short8 aqA[2], aqB[2];
    {
        const bf16* qr = qbase + (size_t)(qtA * 64 + 16 * w + l15) * QKSTRIDE;
        aqA[0] = *reinterpret_cast<const short8*>(qr + lq * 8);
        aqA[1] = *reinterpret_cast<const short8*>(qr + 32 + lq * 8);
        qr = qbase + (size_t)(qtB * 64 + 16 * w + l15) * QKSTRIDE;
        aqB[0] = *reinterpret_cast<const short8*>(qr + lq * 8);
        aqB[1] = *reinterpret_cast<const short8*>(qr + 32 + lq * 8);
    }

    const int srow = lane >> 2;
    const int scol = (((lane & 3) ^ (srow & 3))) * 8;   // staging swizzle
    const int rsw = lq ^ (l15 & 3);                     // K/V frag read chunk
    const int psw = lq ^ (l15 >> 2);                    // Ps frag read chunk

    const short8 ones8 = {0x3F80, 0x3F80, 0x3F80, 0x3F80,
                          0x3F80, 0x3F80, 0x3F80, 0x3F80};  // bf16 1.0 x8

    floatx4 accA[4], accB[4], lAcc[2];
    #pragma unroll
    for (int nt = 0; nt < 4; ++nt) {
        accA[nt] = (floatx4){0.f, 0.f, 0.f, 0.f};
        accB[nt] = (floatx4){0.f, 0.f, 0.f, 0.f};
    }
    lAcc[0] = (floatx4){0.f, 0.f, 0.f, 0.f};
    lAcc[1] = (floatx4){0.f, 0.f, 0.f, 0.f};

    const int rowloc = 16 * w + lq * 4;

    // max-free softmax + PV + MFMA-l for one q-tile
    auto softmax_pv = [&](floatx4* accS, floatx4* accO, floatx4& accL,
                          bool diag, int cur) {
        #pragma unroll
        for (int nt = 0; nt < 4; ++nt) {
            const int colloc = nt * 16 + l15;
            #pragma unroll
            for (int r = 0; r < 4; ++r) {
                float e = __builtin_amdgcn_exp2f(accS[nt][r]);
                if (diag && colloc > rowloc + r) e = 0.f;
                // store: row = lq*4+r, col = (nt&1)*16 + l15
                // chunk = (nt&1)*2 + (l15>>3), swizzled ^= lq  (stride 40!)
                Ps[w][nt >> 1][lq * 4 + r]
                  [((((nt & 1) * 2 + (l15 >> 3)) ^ lq) * 8) + (l15 & 7)] =
                    __float2bfloat16(e);
            }
        }
        __builtin_amdgcn_s_setprio(1);
        #pragma unroll
        for (int kp = 0; kp < 2; ++kp) {
            const short8 ap = *reinterpret_cast<const short8*>(
                &Ps[w][kp][l15][psw * 8]);
            #pragma unroll
            for (int nt = 0; nt < 4; ++nt) {
                const short8 bv = *reinterpret_cast<const short8*>(
                    &Vt[cur][kp][nt * 16 + l15][rsw * 8]);
                accO[nt] = __builtin_amdgcn_mfma_f32_16x16x32_bf16(
                    ap, bv, accO[nt], 0, 0, 0);
            }
            accL = __builtin_amdgcn_mfma_f32_16x16x32_bf16(
                ap, ones8, accL, 0, 0, 0);
        }
        __builtin_amdgcn_s_setprio(0);
    };

    auto stage = [&](int kt, int buf) {
        #pragma unroll
        for (int p = 0; p < 2; ++p) {
            gload16(kbase + (size_t)(kt * 64 + 16 * w + srow) * QKSTRIDE
                        + p * 32 + scol,
                    &Ks[buf][p][16 * w][0]);
            gload16(vbase + (size_t)(16 * w + srow) * SEQ + kt * 64
                        + p * 32 + scol,
                    &Vt[buf][p][16 * w][0]);
        }
    };

    stage(0, 0);
    __syncthreads();

    for (int kt = 0; kt <= qtB; ++kt) {
        const int cur = kt & 1, nxt = cur ^ 1;
        if (kt < qtB) stage(kt + 1, nxt);

        short8 bk[2][4];
        #pragma unroll
        for (int p = 0; p < 2; ++p)
            #pragma unroll
            for (int nt = 0; nt < 4; ++nt)
                bk[p][nt] = *reinterpret_cast<const short8*>(
                    &Ks[cur][p][nt * 16 + l15][rsw * 8]);

        __builtin_amdgcn_s_setprio(1);
        floatx4 sB[4];
        #pragma unroll
        for (int nt = 0; nt < 4; ++nt) sB[nt] = (floatx4){0.f, 0.f, 0.f, 0.f};
        #pragma unroll
        for (int p = 0; p < 2; ++p)
            #pragma unroll
            for (int nt = 0; nt < 4; ++nt)
                sB[nt] = __builtin_amdgcn_mfma_f32_16x16x32_bf16(
                    aqB[p], bk[p][nt], sB[nt], 0, 0, 0);
        __builtin_amdgcn_s_setprio(0);

        if (kt <= qtA) {
            __builtin_amdgcn_s_setprio(1);
            floatx4 sA[4];
            #pragma unroll
            for (int nt = 0; nt < 4; ++nt) sA[nt] = (floatx4){0.f, 0.f, 0.f, 0.f};
            #pragma unroll
            for (int p = 0; p < 2; ++p)
                #pragma unroll
                for (int nt = 0; nt < 4; ++nt)
                    sA[nt] = __builtin_amdgcn_mfma_f32_16x16x32_bf16(
                        aqA[p], bk[p][nt], sA[nt], 0, 0, 0);
            __builtin_amdgcn_s_setprio(0);
            softmax_pv(sB, accB, lAcc[1], kt == qtB, cur);
            softmax_pv(sA, accA, lAcc[0], kt == qtA, cur);
        } else {
            softmax_pv(sB, accB, lAcc[1], kt == qtB, cur);
        }
        __syncthreads();
    }

    // Epilogue: accL already holds the row sums (replicated across l15).
    auto epilogue = [&](floatx4* accO, floatx4& accL, int qt) {
        #pragma unroll
        for (int r = 0; r < 4; ++r) {
            const float inv = 1.f / accL[r];
            const int qrow = qt * 64 + 16 * w + lq * 4 + r;
            #pragma unroll
            for (int nt = 0; nt < 4; ++nt) {
                O[((size_t)(b * SEQ + qrow)) * D_MODEL + h * DK + nt * 16 + l15] =
                    __float2bfloat16(accO[nt][r] * inv);
            }
        }
    };
    epilogue(accA, lAcc[0], qtA);
    epilogue(accB, lAcc[1], qtB);
}

extern "C" void kernel_launch(void* const* d_in, const int* in_sizes, int n_in,
                              void* d_out, int out_size, void* d_ws, size_t ws_size,
                              hipStream_t stream)
{
    const float* x   = (const float*)d_in[0];
    const int*   pos = (const int*)d_in[1];
    const float* Wq  = (const float*)d_in[2];
    const float* Wk  = (const float*)d_in[3];
    const float* Wv  = (const float*)d_in[4];
    const float* Wo  = (const float*)d_in[5];
    float* out = (float*)d_out;

    bf16* xb    = (bf16*)d_ws;
    bf16* w_all = xb + SEG_X;
    bf16* wob   = w_all + 3 * SEG_W;
    bf16* qkb   = wob + SEG_W;                     // 4096 x 2048 (Q|K roped)
    bf16* vtb   = qkb + (size_t)MROWS * QKSTRIDE;  // 32 bh x 64 d x 2048 s
    bf16* ob    = xb;                              // reuse: x dead after GEMM1

    cast_kernel<<<8192, 256, 0, stream>>>(x, Wq, Wk, Wv, Wo, xb, w_all, wob);
    gemm128_kernel<true><<<dim3(32, 24), 256, 0, stream>>>(
        xb, w_all, qkb, vtb, nullptr, pos);
    flash_attn_kernel<<<dim3(16, 32), 256, 0, stream>>>(qkb, vtb, ob);
    gemm128_kernel<false><<<dim3(32, 8), 256, 0, stream>>>(
        ob, wob, nullptr, nullptr, out, nullptr);
}